// Round 6
// baseline (91.410 us; speedup 1.0000x reference)
//
#include <hip/hip_runtime.h>

#define N 2048
#define T 32
#define D 128
#define BT 32
#define MT (N / BT)                // 64 row-blocks
#define NTILES (MT * (MT + 1) / 2) // 2080 upper-triangular tiles
#define PSTR 20                    // hinge LDS row stride (16 data + 4 pad)

typedef float floatx4 __attribute__((ext_vector_type(4)));
typedef short bf16x8 __attribute__((ext_vector_type(8)));

// s_waitcnt lgkmcnt(0) only — gfx9 encoding 0xc07f (single-wave WG: no barrier).
#define LGKM0() __builtin_amdgcn_s_waitcnt(0xc07f)

// Split fp32 -> truncated-bf16 (h) + truncated-bf16 of exact remainder (l).
// Gram via h*h + h*l + l*h drops only l*l (<= 2^-16 rel) — verified exact to
// print precision in R5 (absmax 0.0).
__device__ __forceinline__ void split8(float4 a, float4 b, bf16x8& h, bf16x8& l) {
  float v[8] = {a.x, a.y, a.z, a.w, b.x, b.y, b.z, b.w};
#pragma unroll
  for (int i = 0; i < 8; ++i) {
    unsigned u = __float_as_uint(v[i]);
    h[i] = (short)(u >> 16);
    float lo = v[i] - __uint_as_float(u & 0xffff0000u);
    l[i] = (short)(__float_as_uint(lo) >> 16);
  }
}

__device__ __forceinline__ float sumsq8(float4 a, float4 b) {
  return a.x * a.x + a.y * a.y + a.z * a.z + a.w * a.w +
         b.x * b.x + b.y * b.y + b.z * b.z + b.w * b.w;
}

// tile id -> (a,b), a<=b, upper-triangular over MT x MT
__device__ __forceinline__ void tile_decode(int t, int& a, int& b) {
  a = (int)((2 * MT + 1 -
             sqrtf((float)((2 * MT + 1) * (2 * MT + 1) - 8 * t))) * 0.5f);
  while (a > 0 && t < a * MT - a * (a - 1) / 2) --a;
  while (t >= (a + 1) * MT - (a + 1) * a / 2) ++a;
  b = a + (t - (a * MT - a * (a - 1) / 2));
}

// ---------------------------------------------------------------------------
// Phase 1: per 32x32 tile, sd[j][k] = scale*(1 - cos(Xa_j, Xb_k)) via
// split-bf16 MFMA (R5's dot phase). Output layout is flat per-lane:
// sd_out[tile*1024 + (I*8+J*4+r)*64 + tid] — 256 B coalesced stores, and the
// hinge kernel reads with the IDENTICAL (quad,m) lane mapping.
// ---------------------------------------------------------------------------
__global__ __launch_bounds__(64) void gram_kernel(
    const float* __restrict__ X,        // [N][D]
    const float* __restrict__ scale_p,  // [1]
    float* __restrict__ sd_out) {       // [NTILES*1024]
  __shared__ float nrmA[BT], nrmB[BT];

  int a, b;
  tile_decode(blockIdx.x, a, b);

  const int tid  = threadIdx.x;
  const int m    = tid & 15;
  const int quad = tid >> 4;
  const int aRow0 = a * BT, bRow0 = b * BT;
  const float scale = scale_p[0];

  floatx4 acc[2][2];
#pragma unroll
  for (int I = 0; I < 2; ++I)
#pragma unroll
    for (int J = 0; J < 2; ++J) acc[I][J] = (floatx4){0.f, 0.f, 0.f, 0.f};
  float ssA[2] = {0.f, 0.f}, ssB[2] = {0.f, 0.f};

  const float* xa0 = X + (size_t)(aRow0 + m) * D + quad * 8;
  const float* xb0 = X + (size_t)(bRow0 + m) * D + quad * 8;

#pragma unroll
  for (int ks = 0; ks < 4; ++ks) {
    bf16x8 hA[2], lA[2], hB[2], lB[2];
#pragma unroll
    for (int I = 0; I < 2; ++I) {
      float4 u0 = *(const float4*)(xa0 + (size_t)I * 16 * D + ks * 32);
      float4 u1 = *(const float4*)(xa0 + (size_t)I * 16 * D + ks * 32 + 4);
      ssA[I] += sumsq8(u0, u1);
      split8(u0, u1, hA[I], lA[I]);
      float4 w0 = *(const float4*)(xb0 + (size_t)I * 16 * D + ks * 32);
      float4 w1 = *(const float4*)(xb0 + (size_t)I * 16 * D + ks * 32 + 4);
      ssB[I] += sumsq8(w0, w1);
      split8(w0, w1, hB[I], lB[I]);
    }
#pragma unroll
    for (int I = 0; I < 2; ++I)
#pragma unroll
      for (int J = 0; J < 2; ++J) {
        acc[I][J] = __builtin_amdgcn_mfma_f32_16x16x32_bf16(hA[I], hB[J],
                                                            acc[I][J], 0, 0, 0);
        acc[I][J] = __builtin_amdgcn_mfma_f32_16x16x32_bf16(hA[I], lB[J],
                                                            acc[I][J], 0, 0, 0);
        acc[I][J] = __builtin_amdgcn_mfma_f32_16x16x32_bf16(lA[I], hB[J],
                                                            acc[I][J], 0, 0, 0);
      }
  }

  // norms: reduce row-m partials across the 4 quads
#pragma unroll
  for (int I = 0; I < 2; ++I) {
    ssA[I] += __shfl_xor(ssA[I], 16, 64);
    ssA[I] += __shfl_xor(ssA[I], 32, 64);
    ssB[I] += __shfl_xor(ssB[I], 16, 64);
    ssB[I] += __shfl_xor(ssB[I], 32, 64);
  }
  if (quad == 0) {
#pragma unroll
    for (int I = 0; I < 2; ++I) {
      nrmA[16 * I + m] = rsqrtf(ssA[I]);
      nrmB[16 * I + m] = rsqrtf(ssB[I]);
    }
  }
  LGKM0();

  float na[2][4], nb[2];
#pragma unroll
  for (int I = 0; I < 2; ++I) {
#pragma unroll
    for (int r = 0; r < 4; ++r) na[I][r] = nrmA[16 * I + quad * 4 + r];
    nb[I] = nrmB[16 * I + m];
  }
  float* out = sd_out + (size_t)blockIdx.x * 1024 + tid;
#pragma unroll
  for (int I = 0; I < 2; ++I)
#pragma unroll
    for (int J = 0; J < 2; ++J)
#pragma unroll
      for (int r = 0; r < 4; ++r)
        out[(I * 8 + J * 4 + r) * 64] =
            scale * (1.0f - acc[I][J][r] * na[I][r] * nb[J]);
}

// ---------------------------------------------------------------------------
// Phase 2: hinge over (tile, t-half). 4160 single-wave blocks -> 4 waves/SIMD.
// Thread (quad,m) owns the same 16 pairs as in gram_kernel; sd loads are the
// mirror of gram's stores (256 B coalesced). sum_t max(|dp|,s) - 16*s.
// ---------------------------------------------------------------------------
__global__ __launch_bounds__(64) void hinge_kernel(
    const float* __restrict__ pred,     // [N][T]
    const float* __restrict__ sd_in,    // [NTILES*1024]
    double* __restrict__ partials) {    // [2*NTILES]
  __shared__ float Pa[BT * PSTR], Pb[BT * PSTR];

  const int tile = blockIdx.x >> 1;
  const int th   = blockIdx.x & 1;     // t-half: 0 or 1
  int a, b;
  tile_decode(tile, a, b);

  const int tid  = threadIdx.x;
  const int m    = tid & 15;
  const int quad = tid >> 4;
  const int aRow0 = a * BT, bRow0 = b * BT;

  // stage 16 t-values per row (2 threads/row, 8 floats each)
  {
    const int srow = tid >> 1, co = (tid & 1) << 3;
    const float* par = pred + (size_t)(aRow0 + srow) * T + th * 16 + co;
    const float* pbr = pred + (size_t)(bRow0 + srow) * T + th * 16 + co;
    *(float4*)(&Pa[srow * PSTR + co])     = *(const float4*)(par);
    *(float4*)(&Pa[srow * PSTR + co + 4]) = *(const float4*)(par + 4);
    *(float4*)(&Pb[srow * PSTR + co])     = *(const float4*)(pbr);
    *(float4*)(&Pb[srow * PSTR + co + 4]) = *(const float4*)(pbr + 4);
  }

  // load sd (mirror of gram's store addressing)
  const float* sin_ = sd_in + (size_t)tile * 1024 + tid;
  float sd[2][2][4], ps[2][2][4];
#pragma unroll
  for (int I = 0; I < 2; ++I)
#pragma unroll
    for (int J = 0; J < 2; ++J)
#pragma unroll
      for (int r = 0; r < 4; ++r) {
        sd[I][J][r] = sin_[(I * 8 + J * 4 + r) * 64];
        ps[I][J][r] = 0.0f;
      }
  LGKM0();  // pred staging visible (single wave)

#pragma unroll
  for (int t4 = 0; t4 < 4; ++t4) {
    float4 qb[2];
    qb[0] = *(const float4*)(&Pb[m * PSTR + t4 * 4]);
    qb[1] = *(const float4*)(&Pb[(16 + m) * PSTR + t4 * 4]);
#pragma unroll
    for (int I = 0; I < 2; ++I)
#pragma unroll
      for (int r = 0; r < 4; ++r) {
        float4 qa = *(const float4*)(&Pa[(16 * I + quad * 4 + r) * PSTR + t4 * 4]);
#pragma unroll
        for (int J = 0; J < 2; ++J) {
          float s = sd[I][J][r];
          ps[I][J][r] += fmaxf(fabsf(qa.x - qb[J].x), s) +
                         fmaxf(fabsf(qa.y - qb[J].y), s) +
                         fmaxf(fabsf(qa.z - qb[J].z), s) +
                         fmaxf(fabsf(qa.w - qb[J].w), s);
        }
      }
  }

  float tsum = 0.0f;
#pragma unroll
  for (int I = 0; I < 2; ++I)
#pragma unroll
    for (int J = 0; J < 2; ++J)
#pragma unroll
      for (int r = 0; r < 4; ++r) {
        int j = aRow0 + 16 * I + quad * 4 + r;
        int k = bRow0 + 16 * J + m;
        tsum += (k > j) ? (ps[I][J][r] - 16.0f * sd[I][J][r]) : 0.0f;
      }

  double dsum = (double)tsum;
#pragma unroll
  for (int off = 32; off > 0; off >>= 1) dsum += __shfl_down(dsum, off, 64);
  if (tid == 0) partials[blockIdx.x] = dsum;
}

// ---------------------------------------------------------------------------
// Finalize: sum 2*NTILES partials, scale, clamp.
// ---------------------------------------------------------------------------
__global__ __launch_bounds__(256) void finalize_kernel(
    const double* __restrict__ partials, const float* __restrict__ target,
    float* __restrict__ out) {
  __shared__ double red[4];
  double s = 0.0;
  for (int i = threadIdx.x; i < 2 * NTILES; i += 256) s += partials[i];
#pragma unroll
  for (int off = 32; off > 0; off >>= 1) s += __shfl_down(s, off, 64);
  int wave = threadIdx.x >> 6, lane = threadIdx.x & 63;
  if (lane == 0) red[wave] = s;
  __syncthreads();
  if (threadIdx.x == 0) {
    double tot = red[0] + red[1] + red[2] + red[3];
    double mf  = 2.0 * tot / ((double)N * (double)(N - 1) * (double)T);
    double r   = mf - (double)target[0];
    out[0] = (float)(r > 0.0 ? r : 0.0);
  }
}

extern "C" void kernel_launch(void* const* d_in, const int* in_sizes, int n_in,
                              void* d_out, int out_size, void* d_ws, size_t ws_size,
                              hipStream_t stream) {
  const float* target = (const float*)d_in[0];
  const float* pred   = (const float*)d_in[1];
  const float* X      = (const float*)d_in[2];
  // d_in[3] = ntimes (==32, hardcoded); d_in[4] = scale
  const float* scale  = (const float*)d_in[4];

  float*  sd       = (float*)d_ws;                          // 8.5 MB
  double* partials = (double*)((char*)d_ws + (16u << 20));  // 2*NTILES doubles

  gram_kernel<<<dim3(NTILES), dim3(64), 0, stream>>>(X, scale, sd);
  hinge_kernel<<<dim3(2 * NTILES), dim3(64), 0, stream>>>(pred, sd, partials);
  finalize_kernel<<<dim3(1), dim3(256), 0, stream>>>(partials, target,
                                                     (float*)d_out);
}

// Round 7
// 91.217 us; speedup vs baseline: 1.0021x; 1.0021x over previous
//
#include <hip/hip_runtime.h>

#define N 2048
#define T 32
#define D 128
#define BT 32
#define MT (N / BT)                // 64 row-blocks for gram tiles
#define NTILES (MT * (MT + 1) / 2) // 2080 upper-triangular tiles
#define HJ 8                       // hinge j-rows per block
#define NHBLK 4224                 // sum_{kb=0}^{31} 8*(kb+1)

typedef float floatx4 __attribute__((ext_vector_type(4)));
typedef short bf16x8 __attribute__((ext_vector_type(8)));

// tile id -> (a,b), a<=b, upper-triangular over MT x MT
__device__ __forceinline__ void tile_decode(int t, int& a, int& b) {
  a = (int)((2 * MT + 1 -
             sqrtf((float)((2 * MT + 1) * (2 * MT + 1) - 8 * t))) * 0.5f);
  while (a > 0 && t < a * MT - a * (a - 1) / 2) --a;
  while (t >= (a + 1) * MT - (a + 1) * a / 2) ++a;
  b = a + (t - (a * MT - a * (a - 1) / 2));
}

// ---------------------------------------------------------------------------
// Kernel 1: normalize each X row and split into truncated-bf16 high/low
// planes (xn = h + l + eps, |eps| <= 2^-17|xn|). Done ONCE — removes ~640
// redundant split VALU ops per gram wave (each row is used by ~65 tiles).
// One wave per row; lane handles 2 elements; packed dword stores.
// ---------------------------------------------------------------------------
__global__ __launch_bounds__(256) void presplit_kernel(
    const float* __restrict__ X, unsigned* __restrict__ hX,
    unsigned* __restrict__ lX) {
  const int row  = blockIdx.x * 4 + (threadIdx.x >> 6);
  const int lane = threadIdx.x & 63;
  float2 v = ((const float2*)(X + (size_t)row * D))[lane];
  float ss = v.x * v.x + v.y * v.y;
#pragma unroll
  for (int off = 32; off > 0; off >>= 1) ss += __shfl_xor(ss, off, 64);
  const float rn = rsqrtf(ss);
  const float ax = v.x * rn, ay = v.y * rn;
  const unsigned ux = __float_as_uint(ax), uy = __float_as_uint(ay);
  const float lxf = ax - __uint_as_float(ux & 0xffff0000u);  // exact
  const float lyf = ay - __uint_as_float(uy & 0xffff0000u);  // exact
  hX[(size_t)row * 64 + lane] = (ux >> 16) | ((uy >> 16) << 16);
  lX[(size_t)row * 64 + lane] =
      (__float_as_uint(lxf) >> 16) | ((__float_as_uint(lyf) >> 16) << 16);
}

// ---------------------------------------------------------------------------
// Kernel 2: per 32x32 tile, sd[j][k] = scale*(1 - cos) via split-bf16 MFMA
// (hh + hl + lh; ll term <= 2^-16 rel — verified exact-to-print in R5/R6).
// Inputs pre-normalized/pre-split: no LDS, no norms, no shuffles — 32 global
// b128 loads + 48 MFMA + 16 stores per wave. Output DENSE sdm[j*N+k] so the
// hinge kernel reads one coalesced dword per (j, k-block).
// ---------------------------------------------------------------------------
__global__ __launch_bounds__(64) void gram_kernel(
    const unsigned short* __restrict__ hX, const unsigned short* __restrict__ lX,
    const float* __restrict__ scale_p, float* __restrict__ sdm) {
  int a, b;
  tile_decode(blockIdx.x, a, b);

  const int tid  = threadIdx.x;
  const int m    = tid & 15;
  const int quad = tid >> 4;
  const int aRow0 = a * BT, bRow0 = b * BT;
  const float scale = scale_p[0];

  floatx4 acc[2][2];
#pragma unroll
  for (int I = 0; I < 2; ++I)
#pragma unroll
    for (int J = 0; J < 2; ++J) acc[I][J] = (floatx4){0.f, 0.f, 0.f, 0.f};

  const unsigned short* ha0 = hX + (size_t)(aRow0 + m) * D + quad * 8;
  const unsigned short* la0 = lX + (size_t)(aRow0 + m) * D + quad * 8;
  const unsigned short* hb0 = hX + (size_t)(bRow0 + m) * D + quad * 8;
  const unsigned short* lb0 = lX + (size_t)(bRow0 + m) * D + quad * 8;

#pragma unroll
  for (int ks = 0; ks < 4; ++ks) {
    bf16x8 hA[2], lA[2], hB[2], lB[2];
#pragma unroll
    for (int I = 0; I < 2; ++I) {
      hA[I] = *(const bf16x8*)(ha0 + (size_t)I * 16 * D + ks * 32);
      lA[I] = *(const bf16x8*)(la0 + (size_t)I * 16 * D + ks * 32);
      hB[I] = *(const bf16x8*)(hb0 + (size_t)I * 16 * D + ks * 32);
      lB[I] = *(const bf16x8*)(lb0 + (size_t)I * 16 * D + ks * 32);
    }
#pragma unroll
    for (int I = 0; I < 2; ++I)
#pragma unroll
      for (int J = 0; J < 2; ++J) {
        acc[I][J] = __builtin_amdgcn_mfma_f32_16x16x32_bf16(hA[I], hB[J],
                                                            acc[I][J], 0, 0, 0);
        acc[I][J] = __builtin_amdgcn_mfma_f32_16x16x32_bf16(hA[I], lB[J],
                                                            acc[I][J], 0, 0, 0);
        acc[I][J] = __builtin_amdgcn_mfma_f32_16x16x32_bf16(lA[I], hB[J],
                                                            acc[I][J], 0, 0, 0);
      }
  }

  // C layout (verified R5): row = 16I + quad*4 + r, col = 16J + m
#pragma unroll
  for (int I = 0; I < 2; ++I)
#pragma unroll
    for (int J = 0; J < 2; ++J)
#pragma unroll
      for (int r = 0; r < 4; ++r) {
        const int row = aRow0 + 16 * I + quad * 4 + r;
        const int col = bRow0 + 16 * J + m;
        sdm[(size_t)row * N + col] = scale * (1.0f - acc[I][J][r]);
      }
}

// ---------------------------------------------------------------------------
// Kernel 3: hinge. Block = (8-row j-slab) x (64-col k-block), 4224 blocks ->
// ~4 waves/SIMD. Lane owns column k: its pred row lives in 32 VGPRs; per j,
// pa is wave-uniform (scalarizable loads) and sd is one coalesced dword.
// Pure-VALU t-loop (sub + max(|d|,s) + add), 4 independent accumulators,
// zero LDS. Identity sum_t max(|d|,s) - T*s == sum_t max(0,|d|-s) (exact
// for any sign of s). Below-diagonal sd reads hit poisoned ws (finite float,
// not NaN) and are discarded by the k>j mask.
// ---------------------------------------------------------------------------
__global__ __launch_bounds__(64) void hinge_kernel(
    const float* __restrict__ pred, const float* __restrict__ sdm,
    double* __restrict__ partials) {
  const int bid = blockIdx.x;
  // base(kb) = 4*kb*(kb+1); kb = floor((-1+sqrt(1+bid))/2) with fixup
  int kb = (int)((-1.0f + sqrtf(1.0f + (float)bid)) * 0.5f);
  while (kb > 0 && 4 * kb * (kb + 1) > bid) --kb;
  while (4 * (kb + 1) * (kb + 2) <= bid) ++kb;
  const int jb = bid - 4 * kb * (kb + 1);

  const int lane = threadIdx.x;
  const int k    = kb * 64 + lane;
  const int j0   = jb * HJ;

  // lane's own pred row (32 floats = 32 VGPRs)
  float4 pb[8];
  const float4* pk = (const float4*)(pred + (size_t)k * T);
#pragma unroll
  for (int q = 0; q < 8; ++q) pb[q] = pk[q];

  float tsum = 0.0f;
#pragma unroll 2
  for (int jj = 0; jj < HJ; ++jj) {
    const int j = j0 + jj;
    const float sdv = sdm[(size_t)j * N + kb * 64 + lane];  // coalesced 256B
    const float4* pj = (const float4*)(pred + (size_t)j * T);  // wave-uniform
    float ps0 = 0.f, ps1 = 0.f, ps2 = 0.f, ps3 = 0.f;
#pragma unroll
    for (int q = 0; q < 8; ++q) {
      float4 pa = pj[q];
      ps0 += fmaxf(fabsf(pa.x - pb[q].x), sdv);
      ps1 += fmaxf(fabsf(pa.y - pb[q].y), sdv);
      ps2 += fmaxf(fabsf(pa.z - pb[q].z), sdv);
      ps3 += fmaxf(fabsf(pa.w - pb[q].w), sdv);
    }
    const float pss = (ps0 + ps1) + (ps2 + ps3);
    tsum += (k > j) ? (pss - 32.0f * sdv) : 0.0f;
  }

  double dsum = (double)tsum;
#pragma unroll
  for (int off = 32; off > 0; off >>= 1) dsum += __shfl_down(dsum, off, 64);
  if (lane == 0) partials[bid] = dsum;
}

// ---------------------------------------------------------------------------
// Kernel 4: sum partials, scale, clamp.
// ---------------------------------------------------------------------------
__global__ __launch_bounds__(256) void finalize_kernel(
    const double* __restrict__ partials, const float* __restrict__ target,
    float* __restrict__ out) {
  __shared__ double red[4];
  double s = 0.0;
  for (int i = threadIdx.x; i < NHBLK; i += 256) s += partials[i];
#pragma unroll
  for (int off = 32; off > 0; off >>= 1) s += __shfl_down(s, off, 64);
  int wave = threadIdx.x >> 6, lane = threadIdx.x & 63;
  if (lane == 0) red[wave] = s;
  __syncthreads();
  if (threadIdx.x == 0) {
    double tot = red[0] + red[1] + red[2] + red[3];
    double mf  = 2.0 * tot / ((double)N * (double)(N - 1) * (double)T);
    double r   = mf - (double)target[0];
    out[0] = (float)(r > 0.0 ? r : 0.0);
  }
}

extern "C" void kernel_launch(void* const* d_in, const int* in_sizes, int n_in,
                              void* d_out, int out_size, void* d_ws, size_t ws_size,
                              hipStream_t stream) {
  const float* target = (const float*)d_in[0];
  const float* pred   = (const float*)d_in[1];
  const float* X      = (const float*)d_in[2];
  // d_in[3] = ntimes (==32, hardcoded); d_in[4] = scale
  const float* scale  = (const float*)d_in[4];

  // ws layout: dense sd matrix [N][N] fp32 (16 MB), then bf16 planes, partials
  float*    sdm      = (float*)d_ws;
  unsigned* hX       = (unsigned*)((char*)d_ws + (16u << 20));
  unsigned* lX       = (unsigned*)((char*)d_ws + (17u << 20));
  double*   partials = (double*)((char*)d_ws + (18u << 20));

  presplit_kernel<<<dim3(N / 4), dim3(256), 0, stream>>>(X, hX, lX);
  gram_kernel<<<dim3(NTILES), dim3(64), 0, stream>>>(
      (const unsigned short*)hX, (const unsigned short*)lX, scale, sdm);
  hinge_kernel<<<dim3(NHBLK), dim3(64), 0, stream>>>(pred, sdm, partials);
  finalize_kernel<<<dim3(1), dim3(256), 0, stream>>>(partials, target,
                                                     (float*)d_out);
}